// Round 5
// baseline (1109.696 us; speedup 1.0000x reference)
//
#include <hip/hip_runtime.h>
#include <math.h>

// (P, C, NX, NY, NT) = (2, 1, 128, 128, 8), T = 128
// Layout: idx = pp<<17 | X<<10 | Y<<3 | T
// R4: persistent cooperative kernel. One launch; 32 groups x 4 fused steps
// with a hand-rolled grid barrier between groups. Inner structure = R2
// (verified 285 us): half-T-columns, 768 thr = 12 waves/CU, halo 4,
// redundancy 1.67x, b128 LDS staging, 1 barrier/substep.
// Persistence wins: xn/lam loaded once (not 32x); own threads never
// round-trip D1/D2 (bf16 rounding applied in-register, bitwise identical
// to pack->unpack); no 31x kernel dispatch/teardown.
#define NSITES (2 * 128 * 128 * 8)      // 262144
#define NBLK   256                      // 16 bx * 8 by * 2 pp
#define NSUP   32                       // 32 groups x 4 fused steps = 128
#define NSYNC  (NSUP - 1)               // 31 grid syncs per invocation
#define TLX    16                       // staged cols x: 8 own + 4+4 halo
#define TLY    24                       // staged cols y: 16 own + 4+4 halo
#define NCOL   (TLX * TLY)              // 384 columns
#define NTHR   (NCOL * 2)               // 768 threads, 2 per column

// monotonic grid-barrier counter; never reset (base recovered by rounding
// down to a multiple of NSYNC*NBLK — arrivals per invocation = exactly that)
__device__ unsigned g_bar = 0;

union F4 { float4 v; float f[4]; };
union U4 { uint4 v; unsigned w[4]; };

// bf16 helpers (RNE). Every block rounds identical register values
// identically, so cross-block redundant-compute consistency is bitwise-exact.
__device__ __forceinline__ unsigned bf_rnd(float v) {
    const unsigned u = __float_as_uint(v);
    return (u + 0x7FFFu + ((u >> 16) & 1u)) >> 16;
}
__device__ __forceinline__ float bf_lo(unsigned p) { return __uint_as_float(p << 16); }
__device__ __forceinline__ float bf_hi(unsigned p) { return __uint_as_float(p & 0xFFFF0000u); }
__device__ __forceinline__ unsigned pk_bf2(float lo, float hi) {
    return bf_rnd(lo) | (bf_rnd(hi) << 16);
}
__device__ __forceinline__ float bf_round(float v) {   // == bf_lo(bf_rnd(v))
    return __uint_as_float(bf_rnd(v) << 16);
}

__global__ __launch_bounds__(NTHR, 3) void pdhg_persist(
    const float* __restrict__ x,
    const float* __restrict__ lam,
    const float* __restrict__ tau_p,
    const float* __restrict__ sigma_p,
    const float* __restrict__ theta_p,
    unsigned long long* __restrict__ D1g,   // 2 slots bf16x4 {xb,q0,q1,q2}
    unsigned long long* __restrict__ D2g,   // 2 slots fp32x2 {p,x0}
    float* __restrict__ out_final)
{
    __shared__ float4 Lxb[2][NTHR];   // 24 KB  xb fp32x4 (4 T of one chunk)
    __shared__ uint4  Lqq[2][NTHR];   // 24 KB  bf16x2 {q0,q1} x4 T

    // XCD-arc swizzle (L2-locality heuristic only)
    const int b  = 32 * (blockIdx.x & 7) + (blockIdx.x >> 3);
    const int pp = b >> 7;
    const int rr = b & 127;
    const int bx = rr >> 3;        // [0,16)
    const int by = rr & 7;         // [0,8)

    const int t   = threadIdx.x;   // [0,768)
    const int tm  = t & 1;         // T-chunk: sites tm*4 .. tm*4+3
    const int col = t >> 1;        // [0,384)
    const int lx  = col / TLY;     // [0,16)
    const int ly  = col - lx * TLY;// [0,24)

    const int X  = ((bx << 3) + lx - 4) & 127;
    const int Y  = ((by << 4) + ly - 4) & 127;
    const int Xm = (X + 127) & 127;
    const int Ym = (Y + 127) & 127;

    const int gcol = (pp << 17) | (X << 10) | (Y << 3);   // site idx of T=0
    const int gxm  = (pp << 17) | (Xm << 10) | (Y << 3);
    const int gym  = (pp << 17) | (X << 10) | (Ym << 3);

    const bool comp = (lx >= 1) && (lx < 15) && (ly >= 1) && (ly < 23);
    const bool own  = (lx >= 4) && (lx < 12) && (ly >= 4) && (ly < 20);

    // barrier base for this invocation (see g_bar comment)
    unsigned bar_base = 0;
    if (t == 0) {
        const unsigned v = atomicAdd(&g_bar, 0u);
        bar_base = (v / (unsigned)(NSYNC * NBLK)) * (unsigned)(NSYNC * NBLK);
    }

    const float L = 3.605551275463989f;  // sqrt(13)
    const float s_sig = (1.f / (1.f + __expf(-sigma_p[0]))) / L;
    const float s_tau = (1.f / (1.f + __expf(-tau_p[0]))) / L;
    const float s_th  =  1.f / (1.f + __expf(-theta_p[0]));
    const float inv1s = 1.f / (1.f + s_sig);

    const int c4 = (gcol >> 2) + tm;   // float4 index of this chunk

    // invariant inputs: loaded ONCE (values for non-comp threads unused)
    float xn[4], lamc[4], lamx[4], lamy[4];
    {
        const float4* x4 = (const float4*)x;
        const float4* l4 = (const float4*)lam;
        F4 a;
        a.v = x4[c4];
        #pragma unroll
        for (int j = 0; j < 4; ++j) xn[j] = a.f[j];
        a.v = l4[c4];
        #pragma unroll
        for (int j = 0; j < 4; ++j) lamc[j] = a.f[j];
        a.v = l4[(gxm >> 2) + tm];
        #pragma unroll
        for (int j = 0; j < 4; ++j) lamx[j] = a.f[j];
        a.v = l4[(gym >> 2) + tm];
        #pragma unroll
        for (int j = 0; j < 4; ++j) lamy[j] = a.f[j];
    }
    // lam at the T-1 site of this chunk's first element = partner's lamc[3]
    const float lamtm = __shfl_xor(lamc[3], 1, 64);

    float x0[4], p[4], q0[4], q1[4], q2[4], xb[4];
    #pragma unroll
    for (int j = 0; j < 4; ++j) {       // FIRST-group init (xb = xn everywhere)
        const float v = xn[j];
        x0[j] = v; p[j] = v; xb[j] = v;
        q0[j] = 0.f; q1[j] = 0.f; q2[j] = 0.f;
    }

    auto clip = [](float v, float l) { return fmaxf(-l, fminf(l, v)); };

    // one fused sub-step: compute lx in [4-h,12+h), ly in [4-h,20+h)
    // store-mask = compute-region(h+1): [3-h,13+h) x [3-h,21+h)
    // Double-buffered LDS (pb = h&1): one barrier per sub-step; two barriers
    // separate reuse of the same buffer (grid barrier supplies them across
    // groups). Partner lanes share (lx,ly): masks pairwise-uniform, partner
    // co-active for shfl_xor(1).
    auto substep = [&](const int h) {
        const int pb = h & 1;
        if (lx >= 3 - h && lx < 13 + h && ly >= 3 - h && ly < 21 + h) {
            Lxb[pb][t] = make_float4(xb[0], xb[1], xb[2], xb[3]);
            U4 w;
            w.w[0] = pk_bf2(q0[0], q1[0]); w.w[1] = pk_bf2(q0[1], q1[1]);
            w.w[2] = pk_bf2(q0[2], q1[2]); w.w[3] = pk_bf2(q0[3], q1[3]);
            Lqq[pb][t] = w.v;
        }
        __syncthreads();
        if (lx >= 4 - h && lx < 12 + h && ly >= 4 - h && ly < 20 + h) {
            // T-boundary values from partner chunk (pre-update snapshots)
            const float xb_tp = __shfl_xor(xb[0], 1, 64);  // T+1 past chunk end
            const float xb_tm = __shfl_xor(xb[3], 1, 64);  // T-1 before chunk start
            const float q2_tm = __shfl_xor(q2[3], 1, 64);
            F4 xp, xm, yp, ym; U4 qx, qy;
            xp.v = Lxb[pb][t + 2 * TLY];
            xm.v = Lxb[pb][t - 2 * TLY];
            yp.v = Lxb[pb][t + 2];
            ym.v = Lxb[pb][t - 2];
            qx.v = Lqq[pb][t - 2 * TLY];
            qy.v = Lqq[pb][t - 2];
            float oxb[4], oq2[4];
            #pragma unroll
            for (int j = 0; j < 4; ++j) { oxb[j] = xb[j]; oq2[j] = q2[j]; }
            #pragma unroll
            for (int j = 0; j < 4; ++j) {
                const float ob   = oxb[j];
                const float xbtp = (j < 3) ? oxb[j + 1] : xb_tp;
                const float xbtm = (j > 0) ? oxb[j - 1] : xb_tm;
                const float q2tm = (j > 0) ? oq2[j - 1] : q2_tm;
                const float lT   = (j > 0) ? lamc[j - 1] : lamtm;
                const float pn  = (p[j] + s_sig * (ob - xn[j])) * inv1s;
                const float q0n = clip(q0[j] + s_sig * (xp.f[j] - ob), lamc[j]);
                const float q1n = clip(q1[j] + s_sig * (yp.f[j] - ob), lamc[j]);
                const float q2n = clip(oq2[j] + s_sig * (xbtp - ob), lamc[j]);
                const float q0m = clip(bf_lo(qx.w[j]) + s_sig * (ob - xm.f[j]), lamx[j]);
                const float q1m = clip(bf_hi(qy.w[j]) + s_sig * (ob - ym.f[j]), lamy[j]);
                const float q2m = clip(q2tm + s_sig * (ob - xbtm), lT);
                const float dv  = (q0m - q0n) + (q1m - q1n) + (q2m - q2n);
                const float x1  = x0[j] - s_tau * (pn + dv);
                xb[j] = x1 + s_th * (x1 - x0[j]);
                x0[j] = x1; p[j] = pn;
                q0[j] = q0n; q1[j] = q1n; q2[j] = q2n;
            }
        }
    };

    #pragma unroll 1
    for (int g = 0; g < NSUP; ++g) {
        if (g > 0) {
            // refresh state for this group from slot written at end of g-1
            if (own) {
                // in-register bf16 round == D1 pack->unpack, bitwise.
                // p, x0 stay exact fp32 (D2 round-trip was identity).
                #pragma unroll
                for (int j = 0; j < 4; ++j) {
                    xb[j] = bf_round(xb[j]);
                    q0[j] = bf_round(q0[j]);
                    q1[j] = bf_round(q1[j]);
                    q2[j] = bf_round(q2[j]);
                }
            } else {
                const size_t si = (size_t)((g & 1) ^ 1) * NSITES;
                const uint4* d1 = (const uint4*)(D1g + si);   // 2 sites per uint4
                const int base = (gcol >> 1) + 2 * tm;
                #pragma unroll
                for (int k = 0; k < 2; ++k) {
                    U4 a; a.v = d1[base + k];
                    #pragma unroll
                    for (int m = 0; m < 2; ++m) {
                        const int j = 2 * k + m;
                        const unsigned lo = a.w[2 * m], hi = a.w[2 * m + 1];
                        xb[j] = bf_lo(lo); q0[j] = bf_hi(lo);
                        q1[j] = bf_lo(hi); q2[j] = bf_hi(hi);
                    }
                }
                if (comp) {
                    const float4* d2 = (const float4*)(D2g + si);
                    #pragma unroll
                    for (int k = 0; k < 2; ++k) {
                        F4 a; a.v = d2[base + k];
                        p[2 * k]     = a.f[0]; x0[2 * k]     = a.f[1];
                        p[2 * k + 1] = a.f[2]; x0[2 * k + 1] = a.f[3];
                    }
                }
            }
        }

        substep(3);   // step 4g+1 on 14x22
        substep(2);   // step 4g+2 on 12x20
        substep(1);   // step 4g+3 on 10x18
        substep(0);   // step 4g+4 on  8x16 (own)

        if (g < NSUP - 1) {
            if (own) {
                const size_t so = (size_t)(g & 1) * NSITES;
                uint4*  o1 = (uint4*)(D1g + so);
                float4* o2 = (float4*)(D2g + so);
                const int base = (gcol >> 1) + 2 * tm;
                #pragma unroll
                for (int k = 0; k < 2; ++k) {
                    U4 w;
                    #pragma unroll
                    for (int m = 0; m < 2; ++m) {
                        const int j = 2 * k + m;
                        w.w[2 * m]     = pk_bf2(xb[j], q0[j]);
                        w.w[2 * m + 1] = pk_bf2(q1[j], q2[j]);
                    }
                    o1[base + k] = w.v;
                    F4 d;
                    d.f[0] = p[2 * k];     d.f[1] = x0[2 * k];
                    d.f[2] = p[2 * k + 1]; d.f[3] = x0[2 * k + 1];
                    o2[base + k] = d.v;
                }
            }
            // grid barrier: release own stores, wait all blocks, acquire.
            __syncthreads();                       // block stores drained (vmcnt 0)
            if (t == 0) {
                __threadfence();                   // agent release (L2 wb)
                atomicAdd(&g_bar, 1u);
                const unsigned want = bar_base + (unsigned)((g + 1) * NBLK);
                while (atomicAdd(&g_bar, 0u) < want) __builtin_amdgcn_s_sleep(8);
                __threadfence();                   // agent acquire (L1/L2 inv)
            }
            __syncthreads();
        }
    }

    // final output: authoritative own sites only
    if (own) {
        float4* o4 = (float4*)out_final;
        F4 a;
        a.f[0] = x0[0]; a.f[1] = x0[1]; a.f[2] = x0[2]; a.f[3] = x0[3];
        o4[c4] = a.v;
    }
}

extern "C" void kernel_launch(void* const* d_in, const int* in_sizes, int n_in,
                              void* d_out, int out_size, void* d_ws, size_t ws_size,
                              hipStream_t stream) {
    const float* x   = (const float*)d_in[0];
    const float* lam = (const float*)d_in[1];
    const float* tau = (const float*)d_in[2];
    const float* sig = (const float*)d_in[3];
    const float* th  = (const float*)d_in[4];
    float* out = (float*)d_out;

    // ws layout: D1 (2 slots u64, 4 MB), D2 (2 slots u64, 4 MB)
    unsigned long long* D1 = (unsigned long long*)d_ws;
    unsigned long long* D2 = D1 + 2 * (size_t)NSITES;

    void* args[] = { (void*)&x, (void*)&lam, (void*)&tau, (void*)&sig, (void*)&th,
                     (void*)&D1, (void*)&D2, (void*)&out };
    hipLaunchCooperativeKernel(pdhg_persist, dim3(NBLK), dim3(NTHR),
                               args, 0, stream);
}

// Round 6
// 483.959 us; speedup vs baseline: 2.2930x; 2.2930x over previous
//
#include <hip/hip_runtime.h>
#include <math.h>

// (P, C, NX, NY, NT) = (2, 1, 128, 128, 8), T = 128
// Layout: idx = pp<<17 | X<<10 | Y<<3 | T
// R5: persistent cooperative kernel, FENCE-FREE coherence.
// R4 post-mortem: __threadfence() = full L2 writeback+invalidate per block
// per group (222 MB HBM writes/dispatch, 27 us/group barrier). Fix: all
// cross-block state (D1/D2) moves via agent-scope RELAXED atomics (8B), which
// are point-of-coherency (MALL) accesses -> no fences needed anywhere.
// Spin uses atomic LOADS (read-shared line) + s_sleep, not RMW polling.
// Inner loop = R2 (verified 285 us): half-T-columns, 768 thr = 12 waves/CU,
// halo 4, redundancy 1.67x, b128 LDS staging, 1 barrier/substep.
// Trajectory is bitwise identical to R2 (own threads round in-register).
#define NSITES (2 * 128 * 128 * 8)      // 262144
#define NBLK   256                      // 16 bx * 8 by * 2 pp
#define NSUP   32                       // 32 groups x 4 fused steps = 128
#define NSYNC  (NSUP - 1)               // 31 grid syncs per invocation
#define TLX    16                       // staged cols x: 8 own + 4+4 halo
#define TLY    24                       // staged cols y: 16 own + 4+4 halo
#define NCOL   (TLX * TLY)              // 384 columns
#define NTHR   (NCOL * 2)               // 768 threads, 2 per column

// monotonic grid-barrier counter; never reset (base recovered by rounding
// down to a multiple of NSYNC*NBLK — arrivals per invocation = exactly that).
// Base-read is safe mid-flight: when any block reads it, at most NBLK-1
// arrivals of the current invocation have occurred (< NSYNC*NBLK).
__device__ unsigned g_bar = 0;

union F4 { float4 v; float f[4]; };
union U4 { uint4 v; unsigned w[4]; };
union P2 { float f[2]; unsigned long long u; };

// bf16 helpers (RNE). Every block rounds identical register values
// identically, so cross-block redundant-compute consistency is bitwise-exact.
__device__ __forceinline__ unsigned bf_rnd(float v) {
    const unsigned u = __float_as_uint(v);
    return (u + 0x7FFFu + ((u >> 16) & 1u)) >> 16;
}
__device__ __forceinline__ float bf_lo(unsigned p) { return __uint_as_float(p << 16); }
__device__ __forceinline__ float bf_hi(unsigned p) { return __uint_as_float(p & 0xFFFF0000u); }
__device__ __forceinline__ unsigned pk_bf2(float lo, float hi) {
    return bf_rnd(lo) | (bf_rnd(hi) << 16);
}
__device__ __forceinline__ float bf_round(float v) {   // == bf_lo(bf_rnd(v))
    return __uint_as_float(bf_rnd(v) << 16);
}

__global__ __launch_bounds__(NTHR, 3) void pdhg_persist(
    const float* __restrict__ x,
    const float* __restrict__ lam,
    const float* __restrict__ tau_p,
    const float* __restrict__ sigma_p,
    const float* __restrict__ theta_p,
    unsigned long long* __restrict__ D1g,   // 2 slots, per-site u64 bf16x4 {xb,q0|q1,q2}
    unsigned long long* __restrict__ D2g,   // 2 slots, per-site u64 fp32x2 {p,x0}
    float* __restrict__ out_final)
{
    __shared__ float4 Lxb[2][NTHR];   // 24 KB  xb fp32x4 (4 T of one chunk)
    __shared__ uint4  Lqq[2][NTHR];   // 24 KB  bf16x2 {q0,q1} x4 T

    // XCD-arc swizzle (L2-locality heuristic only)
    const int b  = 32 * (blockIdx.x & 7) + (blockIdx.x >> 3);
    const int pp = b >> 7;
    const int rr = b & 127;
    const int bx = rr >> 3;        // [0,16)
    const int by = rr & 7;         // [0,8)

    const int t   = threadIdx.x;   // [0,768)
    const int tm  = t & 1;         // T-chunk: sites tm*4 .. tm*4+3
    const int col = t >> 1;        // [0,384)
    const int lx  = col / TLY;     // [0,16)
    const int ly  = col - lx * TLY;// [0,24)

    const int X  = ((bx << 3) + lx - 4) & 127;
    const int Y  = ((by << 4) + ly - 4) & 127;
    const int Xm = (X + 127) & 127;
    const int Ym = (Y + 127) & 127;

    const int gcol = (pp << 17) | (X << 10) | (Y << 3);   // site idx of T=0
    const int gxm  = (pp << 17) | (Xm << 10) | (Y << 3);
    const int gym  = (pp << 17) | (X << 10) | (Ym << 3);

    const bool comp = (lx >= 1) && (lx < 15) && (ly >= 1) && (ly < 23);
    const bool own  = (lx >= 4) && (lx < 12) && (ly >= 4) && (ly < 20);

    // barrier base for this invocation (see g_bar comment)
    unsigned bar_base = 0;
    if (t == 0) {
        const unsigned v = __hip_atomic_load(&g_bar, __ATOMIC_RELAXED,
                                             __HIP_MEMORY_SCOPE_AGENT);
        bar_base = (v / (unsigned)(NSYNC * NBLK)) * (unsigned)(NSYNC * NBLK);
    }

    const float L = 3.605551275463989f;  // sqrt(13)
    const float s_sig = (1.f / (1.f + __expf(-sigma_p[0]))) / L;
    const float s_tau = (1.f / (1.f + __expf(-tau_p[0]))) / L;
    const float s_th  =  1.f / (1.f + __expf(-theta_p[0]));
    const float inv1s = 1.f / (1.f + s_sig);

    const int c4    = (gcol >> 2) + tm;    // float4 index of this chunk
    const int sbase = gcol + 4 * tm;       // site index of this chunk's T=tm*4

    // invariant inputs: loaded ONCE (values for non-comp threads unused)
    float xn[4], lamc[4], lamx[4], lamy[4];
    {
        const float4* x4 = (const float4*)x;
        const float4* l4 = (const float4*)lam;
        F4 a;
        a.v = x4[c4];
        #pragma unroll
        for (int j = 0; j < 4; ++j) xn[j] = a.f[j];
        a.v = l4[c4];
        #pragma unroll
        for (int j = 0; j < 4; ++j) lamc[j] = a.f[j];
        a.v = l4[(gxm >> 2) + tm];
        #pragma unroll
        for (int j = 0; j < 4; ++j) lamx[j] = a.f[j];
        a.v = l4[(gym >> 2) + tm];
        #pragma unroll
        for (int j = 0; j < 4; ++j) lamy[j] = a.f[j];
    }
    // lam at the T-1 site of this chunk's first element = partner's lamc[3]
    const float lamtm = __shfl_xor(lamc[3], 1, 64);

    float x0[4], p[4], q0[4], q1[4], q2[4], xb[4];
    #pragma unroll
    for (int j = 0; j < 4; ++j) {       // FIRST-group init (xb = xn everywhere)
        const float v = xn[j];
        x0[j] = v; p[j] = v; xb[j] = v;
        q0[j] = 0.f; q1[j] = 0.f; q2[j] = 0.f;
    }

    auto clip = [](float v, float l) { return fmaxf(-l, fminf(l, v)); };

    // one fused sub-step: compute lx in [4-h,12+h), ly in [4-h,20+h)
    // store-mask = compute-region(h+1): [3-h,13+h) x [3-h,21+h)
    // Double-buffered LDS (pb = h&1): one barrier per sub-step; two barriers
    // separate reuse of the same buffer (grid barrier supplies them across
    // groups). Partner lanes share (lx,ly): masks pairwise-uniform, partner
    // co-active for shfl_xor(1).
    auto substep = [&](const int h) {
        const int pb = h & 1;
        if (lx >= 3 - h && lx < 13 + h && ly >= 3 - h && ly < 21 + h) {
            Lxb[pb][t] = make_float4(xb[0], xb[1], xb[2], xb[3]);
            U4 w;
            w.w[0] = pk_bf2(q0[0], q1[0]); w.w[1] = pk_bf2(q0[1], q1[1]);
            w.w[2] = pk_bf2(q0[2], q1[2]); w.w[3] = pk_bf2(q0[3], q1[3]);
            Lqq[pb][t] = w.v;
        }
        __syncthreads();
        if (lx >= 4 - h && lx < 12 + h && ly >= 4 - h && ly < 20 + h) {
            // T-boundary values from partner chunk (pre-update snapshots)
            const float xb_tp = __shfl_xor(xb[0], 1, 64);  // T+1 past chunk end
            const float xb_tm = __shfl_xor(xb[3], 1, 64);  // T-1 before chunk start
            const float q2_tm = __shfl_xor(q2[3], 1, 64);
            F4 xp, xm, yp, ym; U4 qx, qy;
            xp.v = Lxb[pb][t + 2 * TLY];
            xm.v = Lxb[pb][t - 2 * TLY];
            yp.v = Lxb[pb][t + 2];
            ym.v = Lxb[pb][t - 2];
            qx.v = Lqq[pb][t - 2 * TLY];
            qy.v = Lqq[pb][t - 2];
            float oxb[4], oq2[4];
            #pragma unroll
            for (int j = 0; j < 4; ++j) { oxb[j] = xb[j]; oq2[j] = q2[j]; }
            #pragma unroll
            for (int j = 0; j < 4; ++j) {
                const float ob   = oxb[j];
                const float xbtp = (j < 3) ? oxb[j + 1] : xb_tp;
                const float xbtm = (j > 0) ? oxb[j - 1] : xb_tm;
                const float q2tm = (j > 0) ? oq2[j - 1] : q2_tm;
                const float lT   = (j > 0) ? lamc[j - 1] : lamtm;
                const float pn  = (p[j] + s_sig * (ob - xn[j])) * inv1s;
                const float q0n = clip(q0[j] + s_sig * (xp.f[j] - ob), lamc[j]);
                const float q1n = clip(q1[j] + s_sig * (yp.f[j] - ob), lamc[j]);
                const float q2n = clip(oq2[j] + s_sig * (xbtp - ob), lamc[j]);
                const float q0m = clip(bf_lo(qx.w[j]) + s_sig * (ob - xm.f[j]), lamx[j]);
                const float q1m = clip(bf_hi(qy.w[j]) + s_sig * (ob - ym.f[j]), lamy[j]);
                const float q2m = clip(q2tm + s_sig * (ob - xbtm), lT);
                const float dv  = (q0m - q0n) + (q1m - q1n) + (q2m - q2n);
                const float x1  = x0[j] - s_tau * (pn + dv);
                xb[j] = x1 + s_th * (x1 - x0[j]);
                x0[j] = x1; p[j] = pn;
                q0[j] = q0n; q1[j] = q1n; q2[j] = q2n;
            }
        }
    };

    #pragma unroll 1
    for (int g = 0; g < NSUP; ++g) {
        if (g > 0) {
            // refresh state for this group from slot written at end of g-1
            if (own) {
                // in-register bf16 round == D1 pack->unpack, bitwise.
                // p, x0 stay exact fp32 (D2 round-trip was identity).
                #pragma unroll
                for (int j = 0; j < 4; ++j) {
                    xb[j] = bf_round(xb[j]);
                    q0[j] = bf_round(q0[j]);
                    q1[j] = bf_round(q1[j]);
                    q2[j] = bf_round(q2[j]);
                }
            } else {
                const size_t si = (size_t)((g & 1) ^ 1) * NSITES;
                const unsigned long long* i1 = D1g + si + sbase;
                #pragma unroll
                for (int j = 0; j < 4; ++j) {
                    const unsigned long long d1 =
                        __hip_atomic_load(&i1[j], __ATOMIC_RELAXED,
                                          __HIP_MEMORY_SCOPE_AGENT);
                    const unsigned lo = (unsigned)d1, hi = (unsigned)(d1 >> 32);
                    xb[j] = bf_lo(lo); q0[j] = bf_hi(lo);
                    q1[j] = bf_lo(hi); q2[j] = bf_hi(hi);
                }
                if (comp) {
                    const unsigned long long* i2 = D2g + si + sbase;
                    #pragma unroll
                    for (int j = 0; j < 4; ++j) {
                        P2 a;
                        a.u = __hip_atomic_load(&i2[j], __ATOMIC_RELAXED,
                                                __HIP_MEMORY_SCOPE_AGENT);
                        p[j] = a.f[0]; x0[j] = a.f[1];
                    }
                }
            }
        }

        substep(3);   // step 4g+1 on 14x22
        substep(2);   // step 4g+2 on 12x20
        substep(1);   // step 4g+3 on 10x18
        substep(0);   // step 4g+4 on  8x16 (own)

        if (g < NSUP - 1) {
            if (own) {
                const size_t so = (size_t)(g & 1) * NSITES;
                unsigned long long* o1 = D1g + so + sbase;
                unsigned long long* o2 = D2g + so + sbase;
                #pragma unroll
                for (int j = 0; j < 4; ++j) {
                    const unsigned long long d1 =
                        (unsigned long long)pk_bf2(xb[j], q0[j]) |
                        ((unsigned long long)pk_bf2(q1[j], q2[j]) << 32);
                    __hip_atomic_store(&o1[j], d1, __ATOMIC_RELAXED,
                                       __HIP_MEMORY_SCOPE_AGENT);
                    P2 d; d.f[0] = p[j]; d.f[1] = x0[j];
                    __hip_atomic_store(&o2[j], d.u, __ATOMIC_RELAXED,
                                       __HIP_MEMORY_SCOPE_AGENT);
                }
            }
            // grid barrier, fence-free: __syncthreads drains this block's
            // agent-coherent stores (vmcnt 0 per wave before s_barrier);
            // completion at the coherence point == global visibility.
            __syncthreads();
            if (t == 0) {
                __hip_atomic_fetch_add(&g_bar, 1u, __ATOMIC_RELAXED,
                                       __HIP_MEMORY_SCOPE_AGENT);
                const unsigned want = bar_base + (unsigned)((g + 1) * NBLK);
                while (__hip_atomic_load(&g_bar, __ATOMIC_RELAXED,
                                         __HIP_MEMORY_SCOPE_AGENT) < want)
                    __builtin_amdgcn_s_sleep(2);
            }
            __syncthreads();   // full compiler+hw barrier: halo loads stay after
        }
    }

    // final output: authoritative own sites only (normal stores; kernel-end
    // writeback handles visibility)
    if (own) {
        float4* o4 = (float4*)out_final;
        F4 a;
        a.f[0] = x0[0]; a.f[1] = x0[1]; a.f[2] = x0[2]; a.f[3] = x0[3];
        o4[c4] = a.v;
    }
}

extern "C" void kernel_launch(void* const* d_in, const int* in_sizes, int n_in,
                              void* d_out, int out_size, void* d_ws, size_t ws_size,
                              hipStream_t stream) {
    const float* x   = (const float*)d_in[0];
    const float* lam = (const float*)d_in[1];
    const float* tau = (const float*)d_in[2];
    const float* sig = (const float*)d_in[3];
    const float* th  = (const float*)d_in[4];
    float* out = (float*)d_out;

    // ws layout: D1 (2 slots u64, 4 MB), D2 (2 slots u64, 4 MB)
    unsigned long long* D1 = (unsigned long long*)d_ws;
    unsigned long long* D2 = D1 + 2 * (size_t)NSITES;

    void* args[] = { (void*)&x, (void*)&lam, (void*)&tau, (void*)&sig, (void*)&th,
                     (void*)&D1, (void*)&D2, (void*)&out };
    hipLaunchCooperativeKernel(pdhg_persist, dim3(NBLK), dim3(NTHR),
                               args, 0, stream);
}

// Round 7
// 333.943 us; speedup vs baseline: 3.3230x; 1.4492x over previous
//
#include <hip/hip_runtime.h>
#include <math.h>

// (P, C, NX, NY, NT) = (2, 1, 128, 128, 8), T = 128
// Layout: idx = pp<<17 | X<<10 | Y<<3 | T
// R6: back to multi-launch (R2 structure, verified 285 us) with 2 blocks/CU.
// R4/R5 proved persistent-kernel coherence loses on CDNA4 (fence = L2 flush;
// agent atomics = uncached MALL traffic, 509 MB/dispatch). Launch boundaries
// are the cheap coherence. This round: 512 blocks x 512 thr (own 8x8,
// staged 16x16, halo 4, half-T columns) -> 16 waves/CU in 2 independent
// blocks to hide barrier drains + prologue latency; redundancy 1.67->1.97x.
#define NSITES (2 * 128 * 128 * 8)      // 262144
#define NBLK   512                      // 16 bx * 16 by * 2 pp
#define NSUP   32                       // 32 launches x 4 fused steps = 128
#define TLX    16                       // staged cols x: 8 own + 4+4 halo
#define TLY    16                       // staged cols y: 8 own + 4+4 halo
#define NCOL   (TLX * TLY)              // 256 columns
#define NTHR   (NCOL * 2)               // 512 threads, 2 per column

union F4 { float4 v; float f[4]; };
union U4 { uint4 v; unsigned w[4]; };

// bf16 helpers (RNE). Every block rounds identical register values
// identically, so cross-block redundant-compute consistency is bitwise-exact.
__device__ __forceinline__ unsigned bf_rnd(float v) {
    const unsigned u = __float_as_uint(v);
    return (u + 0x7FFFu + ((u >> 16) & 1u)) >> 16;
}
__device__ __forceinline__ float bf_lo(unsigned p) { return __uint_as_float(p << 16); }
__device__ __forceinline__ float bf_hi(unsigned p) { return __uint_as_float(p & 0xFFFF0000u); }
__device__ __forceinline__ unsigned pk_bf2(float lo, float hi) {
    return bf_rnd(lo) | (bf_rnd(hi) << 16);
}

template <bool FIRST, bool LAST>
__global__ __launch_bounds__(NTHR, 4) void pdhg_col(
    const float* __restrict__ x,
    const float* __restrict__ lam,
    const float* __restrict__ tau_p,
    const float* __restrict__ sigma_p,
    const float* __restrict__ theta_p,
    const unsigned long long* __restrict__ inD1,   // bf16x4 {xb,q0,q1,q2}
    const unsigned long long* __restrict__ inD2,   // fp32x2 {p,x0}
    unsigned long long* __restrict__ outD1,
    unsigned long long* __restrict__ outD2,
    float* __restrict__ out_final)
{
    // [buf][t]: t = col*2 + tm; 16 KB + 16 KB = 32 KB -> 2 blocks/CU
    __shared__ float4 Lxb[2][NTHR];   // xb fp32x4 (4 T of one chunk)
    __shared__ uint4  Lqq[2][NTHR];   // bf16x2 {q0,q1} x4 T

    // XCD-arc swizzle (L2-locality heuristic only): 64 consecutive per XCD
    const int b  = 64 * (blockIdx.x & 7) + (blockIdx.x >> 3);
    const int pp = b >> 8;
    const int rr = b & 255;
    const int bx = rr >> 4;        // [0,16)
    const int by = rr & 15;        // [0,16)

    const int t   = threadIdx.x;   // [0,512)
    const int tm  = t & 1;         // T-chunk: sites tm*4 .. tm*4+3
    const int col = t >> 1;        // [0,256)
    const int lx  = col >> 4;      // [0,16)
    const int ly  = col & 15;      // [0,16)

    const int X  = ((bx << 3) + lx - 4) & 127;
    const int Y  = ((by << 3) + ly - 4) & 127;
    const int Xm = (X + 127) & 127;
    const int Ym = (Y + 127) & 127;

    const int gcol = (pp << 17) | (X << 10) | (Y << 3);   // site idx of T=0
    const int gxm  = (pp << 17) | (Xm << 10) | (Y << 3);
    const int gym  = (pp << 17) | (X << 10) | (Ym << 3);

    // widest computed region (h=3): lx,ly in [1,15)
    const bool comp = (lx >= 1) && (lx < 15) && (ly >= 1) && (ly < 15);

    const float L = 3.605551275463989f;  // sqrt(13)
    const float s_sig = (1.f / (1.f + __expf(-sigma_p[0]))) / L;
    const float s_tau = (1.f / (1.f + __expf(-tau_p[0]))) / L;
    const float s_th  =  1.f / (1.f + __expf(-theta_p[0]));
    const float inv1s = 1.f / (1.f + s_sig);

    const int c4 = (gcol >> 2) + tm;   // float4 index of this chunk

    float xn[4], lamc[4], lamx[4], lamy[4];
    {
        const float4* x4 = (const float4*)x;
        const float4* l4 = (const float4*)lam;
        if (FIRST || comp) {
            F4 a; a.v = x4[c4];
            #pragma unroll
            for (int j = 0; j < 4; ++j) xn[j] = a.f[j];
        } else {
            #pragma unroll
            for (int j = 0; j < 4; ++j) xn[j] = 0.f;
        }
        if (comp) {
            F4 a;
            a.v = l4[c4];
            #pragma unroll
            for (int j = 0; j < 4; ++j) lamc[j] = a.f[j];
            a.v = l4[(gxm >> 2) + tm];
            #pragma unroll
            for (int j = 0; j < 4; ++j) lamx[j] = a.f[j];
            a.v = l4[(gym >> 2) + tm];
            #pragma unroll
            for (int j = 0; j < 4; ++j) lamy[j] = a.f[j];
        } else {
            #pragma unroll
            for (int j = 0; j < 4; ++j) { lamc[j] = 0.f; lamx[j] = 0.f; lamy[j] = 0.f; }
        }
    }
    // lam at the T-1 site of this chunk's first element = partner's lamc[3]
    const float lamtm = __shfl_xor(lamc[3], 1, 64);

    float x0[4], p[4], q0[4], q1[4], q2[4], xb[4];
    if (FIRST) {
        #pragma unroll
        for (int j = 0; j < 4; ++j) {
            const float v = xn[j];
            x0[j] = v; p[j] = v; xb[j] = v;
            q0[j] = 0.f; q1[j] = 0.f; q2[j] = 0.f;
        }
    } else {
        const uint4* d1 = (const uint4*)inD1;       // 2 sites per uint4
        const int base = (gcol >> 1) + 2 * tm;      // 16B-granule index
        #pragma unroll
        for (int k = 0; k < 2; ++k) {
            U4 a; a.v = d1[base + k];
            #pragma unroll
            for (int m = 0; m < 2; ++m) {
                const int j = 2 * k + m;
                const unsigned lo = a.w[2 * m], hi = a.w[2 * m + 1];
                xb[j] = bf_lo(lo); q0[j] = bf_hi(lo);
                q1[j] = bf_lo(hi); q2[j] = bf_hi(hi);
            }
        }
        if (comp) {
            const float4* d2 = (const float4*)inD2;  // 2 sites per float4
            #pragma unroll
            for (int k = 0; k < 2; ++k) {
                F4 a; a.v = d2[base + k];
                p[2 * k]     = a.f[0]; x0[2 * k]     = a.f[1];
                p[2 * k + 1] = a.f[2]; x0[2 * k + 1] = a.f[3];
            }
        } else {
            #pragma unroll
            for (int j = 0; j < 4; ++j) { p[j] = 0.f; x0[j] = 0.f; }
        }
    }

    auto clip = [](float v, float l) { return fmaxf(-l, fminf(l, v)); };

    // one fused sub-step: compute lx,ly in [4-h,12+h)
    // store-mask = compute-region(h+1): [3-h,13+h)
    // Double-buffered LDS (pb = h&1): one barrier per sub-step; two barriers
    // separate reuse of the same buffer. Partner lanes share (lx,ly) so all
    // masks are pairwise-uniform and shfl_xor(1) partners are co-active.
    auto substep = [&](const int h) {
        const int pb = h & 1;
        if (lx >= 3 - h && lx < 13 + h && ly >= 3 - h && ly < 13 + h) {
            Lxb[pb][t] = make_float4(xb[0], xb[1], xb[2], xb[3]);
            U4 w;
            w.w[0] = pk_bf2(q0[0], q1[0]); w.w[1] = pk_bf2(q0[1], q1[1]);
            w.w[2] = pk_bf2(q0[2], q1[2]); w.w[3] = pk_bf2(q0[3], q1[3]);
            Lqq[pb][t] = w.v;
        }
        __syncthreads();
        if (lx >= 4 - h && lx < 12 + h && ly >= 4 - h && ly < 12 + h) {
            // T-boundary values from partner chunk (pre-update snapshots)
            const float xb_tp = __shfl_xor(xb[0], 1, 64);  // T+1 past chunk end
            const float xb_tm = __shfl_xor(xb[3], 1, 64);  // T-1 before chunk start
            const float q2_tm = __shfl_xor(q2[3], 1, 64);
            F4 xp, xm, yp, ym; U4 qx, qy;
            xp.v = Lxb[pb][t + 2 * TLY];
            xm.v = Lxb[pb][t - 2 * TLY];
            yp.v = Lxb[pb][t + 2];
            ym.v = Lxb[pb][t - 2];
            qx.v = Lqq[pb][t - 2 * TLY];
            qy.v = Lqq[pb][t - 2];
            float oxb[4], oq2[4];
            #pragma unroll
            for (int j = 0; j < 4; ++j) { oxb[j] = xb[j]; oq2[j] = q2[j]; }
            #pragma unroll
            for (int j = 0; j < 4; ++j) {
                const float ob   = oxb[j];
                const float xbtp = (j < 3) ? oxb[j + 1] : xb_tp;
                const float xbtm = (j > 0) ? oxb[j - 1] : xb_tm;
                const float q2tm = (j > 0) ? oq2[j - 1] : q2_tm;
                const float lT   = (j > 0) ? lamc[j - 1] : lamtm;
                const float pn  = (p[j] + s_sig * (ob - xn[j])) * inv1s;
                const float q0n = clip(q0[j] + s_sig * (xp.f[j] - ob), lamc[j]);
                const float q1n = clip(q1[j] + s_sig * (yp.f[j] - ob), lamc[j]);
                const float q2n = clip(oq2[j] + s_sig * (xbtp - ob), lamc[j]);
                const float q0m = clip(bf_lo(qx.w[j]) + s_sig * (ob - xm.f[j]), lamx[j]);
                const float q1m = clip(bf_hi(qy.w[j]) + s_sig * (ob - ym.f[j]), lamy[j]);
                const float q2m = clip(q2tm + s_sig * (ob - xbtm), lT);
                const float dv  = (q0m - q0n) + (q1m - q1n) + (q2m - q2n);
                const float x1  = x0[j] - s_tau * (pn + dv);
                xb[j] = x1 + s_th * (x1 - x0[j]);
                x0[j] = x1; p[j] = pn;
                q0[j] = q0n; q1[j] = q1n; q2[j] = q2n;
            }
        }
    };

    substep(3);   // step 4g+1 on 14x14
    substep(2);   // step 4g+2 on 12x12
    substep(1);   // step 4g+3 on 10x10
    substep(0);   // step 4g+4 on  8x8 (own)

    // write authoritative own sites only
    if (lx >= 4 && lx < 12 && ly >= 4 && ly < 12) {
        if (LAST) {
            float4* o4 = (float4*)out_final;
            F4 a;
            a.f[0] = x0[0]; a.f[1] = x0[1]; a.f[2] = x0[2]; a.f[3] = x0[3];
            o4[c4] = a.v;
        } else {
            uint4*  o1 = (uint4*)outD1;
            float4* o2 = (float4*)outD2;
            const int base = (gcol >> 1) + 2 * tm;
            #pragma unroll
            for (int k = 0; k < 2; ++k) {
                U4 w;
                #pragma unroll
                for (int m = 0; m < 2; ++m) {
                    const int j = 2 * k + m;
                    w.w[2 * m]     = pk_bf2(xb[j], q0[j]);
                    w.w[2 * m + 1] = pk_bf2(q1[j], q2[j]);
                }
                o1[base + k] = w.v;
                F4 d;
                d.f[0] = p[2 * k];     d.f[1] = x0[2 * k];
                d.f[2] = p[2 * k + 1]; d.f[3] = x0[2 * k + 1];
                o2[base + k] = d.v;
            }
        }
    }
}

extern "C" void kernel_launch(void* const* d_in, const int* in_sizes, int n_in,
                              void* d_out, int out_size, void* d_ws, size_t ws_size,
                              hipStream_t stream) {
    const float* x   = (const float*)d_in[0];
    const float* lam = (const float*)d_in[1];
    const float* tau = (const float*)d_in[2];
    const float* sig = (const float*)d_in[3];
    const float* th  = (const float*)d_in[4];
    float* out = (float*)d_out;

    // ws layout: D1 (2 slots u64, 4 MB), D2 (2 slots u64, 4 MB)
    unsigned long long* D1 = (unsigned long long*)d_ws;
    unsigned long long* D2 = D1 + 2 * (size_t)NSITES;

    dim3 grid(NBLK), block(NTHR);

    for (int g = 0; g < NSUP; ++g) {
        const size_t si = (size_t)((g + 1) & 1) * NSITES;  // read slot (prev write)
        const size_t so = (size_t)(g & 1) * NSITES;        // write slot
        const unsigned long long *i1 = D1 + si, *i2 = D2 + si;
        unsigned long long *o1 = D1 + so, *o2 = D2 + so;
        if (g == 0) {
            pdhg_col<true, false><<<grid, block, 0, stream>>>(
                x, lam, tau, sig, th, i1, i2, o1, o2, out);
        } else if (g == NSUP - 1) {
            pdhg_col<false, true><<<grid, block, 0, stream>>>(
                x, lam, tau, sig, th, i1, i2, o1, o2, out);
        } else {
            pdhg_col<false, false><<<grid, block, 0, stream>>>(
                x, lam, tau, sig, th, i1, i2, o1, o2, out);
        }
    }
}

// Round 8
// 276.574 us; speedup vs baseline: 4.0123x; 1.2074x over previous
//
#include <hip/hip_runtime.h>
#include <math.h>

// (P, C, NX, NY, NT) = (2, 1, 128, 128, 8), T = 128
// Layout: idx = pp<<17 | X<<10 | Y<<3 | T
// R7 = R2 (verified 285 us: half-T columns, 768 thr = 12 waves/CU, halo 4,
// redundancy 1.67x, b128 LDS staging, 1 barrier/substep) + v_cvt_pk_bf16_f32
// for ALL bf16 packing (LDS staging + D1 epilogue). HW RNE == software RNE
// bitwise on finite values -> trajectory unchanged; saves ~40 VALU/substep
// and ~80 in epilogue per thread (pk_bf2 was 11 bit-ops per packed word).
// Model (R2/R3/R6 fit): T = 32 x 2us overhead + k x work; this cuts k.
#define NSITES (2 * 128 * 128 * 8)      // 262144
#define NBLK   256                      // 16 bx * 8 by * 2 pp
#define NSUP   32                       // 32 launches x 4 fused steps = 128
#define TLX    16                       // staged cols x: 8 own + 4+4 halo
#define TLY    24                       // staged cols y: 16 own + 4+4 halo
#define NCOL   (TLX * TLY)              // 384 columns
#define NTHR   (NCOL * 2)               // 768 threads, 2 per column

union F4 { float4 v; float f[4]; };
union U4 { uint4 v; unsigned w[4]; };

// bf16 helpers. Packing uses HW v_cvt_pk_bf16_f32 (RNE, one inst — T12
// recipe; no builtin on gfx950, inline asm required). Every block rounds
// identical register values identically -> cross-block redundant-compute
// consistency is bitwise-exact.
__device__ __forceinline__ unsigned pk_bf2(float lo, float hi) {
    unsigned r;
    asm("v_cvt_pk_bf16_f32 %0, %1, %2" : "=v"(r) : "v"(lo), "v"(hi));
    return r;
}
__device__ __forceinline__ float bf_lo(unsigned p) { return __uint_as_float(p << 16); }
__device__ __forceinline__ float bf_hi(unsigned p) { return __uint_as_float(p & 0xFFFF0000u); }

template <bool FIRST, bool LAST>
__global__ __launch_bounds__(NTHR, 3) void pdhg_col(
    const float* __restrict__ x,
    const float* __restrict__ lam,
    const float* __restrict__ tau_p,
    const float* __restrict__ sigma_p,
    const float* __restrict__ theta_p,
    const unsigned long long* __restrict__ inD1,   // bf16x4 {xb,q0,q1,q2}
    const unsigned long long* __restrict__ inD2,   // fp32x2 {p,x0}
    unsigned long long* __restrict__ outD1,
    unsigned long long* __restrict__ outD2,
    float* __restrict__ out_final)
{
    // [buf][t]: t = col*2 + tm, so writes/reads are t*16B +/- const (no conflicts)
    __shared__ float4 Lxb[2][NTHR];   // 24 KB  xb fp32x4 (4 T of one chunk)
    __shared__ uint4  Lqq[2][NTHR];   // 24 KB  bf16x2 {q0,q1} x4 T

    // XCD-arc swizzle (L2-locality heuristic only)
    const int b  = 32 * (blockIdx.x & 7) + (blockIdx.x >> 3);
    const int pp = b >> 7;
    const int rr = b & 127;
    const int bx = rr >> 3;        // [0,16)
    const int by = rr & 7;         // [0,8)

    const int t   = threadIdx.x;   // [0,768)
    const int tm  = t & 1;         // T-chunk: sites tm*4 .. tm*4+3
    const int col = t >> 1;        // [0,384)
    const int lx  = col / TLY;     // [0,16)
    const int ly  = col - lx * TLY;// [0,24)

    const int X  = ((bx << 3) + lx - 4) & 127;
    const int Y  = ((by << 4) + ly - 4) & 127;
    const int Xm = (X + 127) & 127;
    const int Ym = (Y + 127) & 127;

    const int gcol = (pp << 17) | (X << 10) | (Y << 3);   // site idx of T=0
    const int gxm  = (pp << 17) | (Xm << 10) | (Y << 3);
    const int gym  = (pp << 17) | (X << 10) | (Ym << 3);

    // widest computed region (h=3): lx in [1,15), ly in [1,23)
    const bool comp = (lx >= 1) && (lx < 15) && (ly >= 1) && (ly < 23);

    const float L = 3.605551275463989f;  // sqrt(13)
    const float s_sig = (1.f / (1.f + __expf(-sigma_p[0]))) / L;
    const float s_tau = (1.f / (1.f + __expf(-tau_p[0]))) / L;
    const float s_th  =  1.f / (1.f + __expf(-theta_p[0]));
    const float inv1s = 1.f / (1.f + s_sig);

    const int c4 = (gcol >> 2) + tm;   // float4 index of this chunk

    float xn[4], lamc[4], lamx[4], lamy[4];
    {
        const float4* x4 = (const float4*)x;
        const float4* l4 = (const float4*)lam;
        if (FIRST || comp) {
            F4 a; a.v = x4[c4];
            #pragma unroll
            for (int j = 0; j < 4; ++j) xn[j] = a.f[j];
        } else {
            #pragma unroll
            for (int j = 0; j < 4; ++j) xn[j] = 0.f;
        }
        if (comp) {
            F4 a;
            a.v = l4[c4];
            #pragma unroll
            for (int j = 0; j < 4; ++j) lamc[j] = a.f[j];
            a.v = l4[(gxm >> 2) + tm];
            #pragma unroll
            for (int j = 0; j < 4; ++j) lamx[j] = a.f[j];
            a.v = l4[(gym >> 2) + tm];
            #pragma unroll
            for (int j = 0; j < 4; ++j) lamy[j] = a.f[j];
        } else {
            #pragma unroll
            for (int j = 0; j < 4; ++j) { lamc[j] = 0.f; lamx[j] = 0.f; lamy[j] = 0.f; }
        }
    }
    // lam at the T-1 site of this chunk's first element = partner's lamc[3]
    const float lamtm = __shfl_xor(lamc[3], 1, 64);

    float x0[4], p[4], q0[4], q1[4], q2[4], xb[4];
    if (FIRST) {
        #pragma unroll
        for (int j = 0; j < 4; ++j) {
            const float v = xn[j];
            x0[j] = v; p[j] = v; xb[j] = v;
            q0[j] = 0.f; q1[j] = 0.f; q2[j] = 0.f;
        }
    } else {
        const uint4* d1 = (const uint4*)inD1;       // 2 sites per uint4
        const int base = (gcol >> 1) + 2 * tm;      // 16B-granule index
        #pragma unroll
        for (int k = 0; k < 2; ++k) {
            U4 a; a.v = d1[base + k];
            #pragma unroll
            for (int m = 0; m < 2; ++m) {
                const int j = 2 * k + m;
                const unsigned lo = a.w[2 * m], hi = a.w[2 * m + 1];
                xb[j] = bf_lo(lo); q0[j] = bf_hi(lo);
                q1[j] = bf_lo(hi); q2[j] = bf_hi(hi);
            }
        }
        if (comp) {
            const float4* d2 = (const float4*)inD2;  // 2 sites per float4
            #pragma unroll
            for (int k = 0; k < 2; ++k) {
                F4 a; a.v = d2[base + k];
                p[2 * k]     = a.f[0]; x0[2 * k]     = a.f[1];
                p[2 * k + 1] = a.f[2]; x0[2 * k + 1] = a.f[3];
            }
        } else {
            #pragma unroll
            for (int j = 0; j < 4; ++j) { p[j] = 0.f; x0[j] = 0.f; }
        }
    }

    auto clip = [](float v, float l) { return fmaxf(-l, fminf(l, v)); };

    // one fused sub-step: compute lx in [4-h,12+h), ly in [4-h,20+h)
    // store-mask = compute-region(h+1): [3-h,13+h) x [3-h,21+h)
    // Double-buffered LDS (pb = h&1): one barrier per sub-step; two barriers
    // separate reuse of the same buffer. Partner lanes share (lx,ly) so all
    // masks are pairwise-uniform and shfl_xor(1) partners are co-active.
    auto substep = [&](const int h) {
        const int pb = h & 1;
        if (lx >= 3 - h && lx < 13 + h && ly >= 3 - h && ly < 21 + h) {
            Lxb[pb][t] = make_float4(xb[0], xb[1], xb[2], xb[3]);
            U4 w;
            w.w[0] = pk_bf2(q0[0], q1[0]); w.w[1] = pk_bf2(q0[1], q1[1]);
            w.w[2] = pk_bf2(q0[2], q1[2]); w.w[3] = pk_bf2(q0[3], q1[3]);
            Lqq[pb][t] = w.v;
        }
        __syncthreads();
        if (lx >= 4 - h && lx < 12 + h && ly >= 4 - h && ly < 20 + h) {
            // T-boundary values from partner chunk (pre-update snapshots)
            const float xb_tp = __shfl_xor(xb[0], 1, 64);  // T+1 past chunk end
            const float xb_tm = __shfl_xor(xb[3], 1, 64);  // T-1 before chunk start
            const float q2_tm = __shfl_xor(q2[3], 1, 64);
            F4 xp, xm, yp, ym; U4 qx, qy;
            xp.v = Lxb[pb][t + 2 * TLY];
            xm.v = Lxb[pb][t - 2 * TLY];
            yp.v = Lxb[pb][t + 2];
            ym.v = Lxb[pb][t - 2];
            qx.v = Lqq[pb][t - 2 * TLY];
            qy.v = Lqq[pb][t - 2];
            float oxb[4], oq2[4];
            #pragma unroll
            for (int j = 0; j < 4; ++j) { oxb[j] = xb[j]; oq2[j] = q2[j]; }
            #pragma unroll
            for (int j = 0; j < 4; ++j) {
                const float ob   = oxb[j];
                const float xbtp = (j < 3) ? oxb[j + 1] : xb_tp;
                const float xbtm = (j > 0) ? oxb[j - 1] : xb_tm;
                const float q2tm = (j > 0) ? oq2[j - 1] : q2_tm;
                const float lT   = (j > 0) ? lamc[j - 1] : lamtm;
                const float pn  = (p[j] + s_sig * (ob - xn[j])) * inv1s;
                const float q0n = clip(q0[j] + s_sig * (xp.f[j] - ob), lamc[j]);
                const float q1n = clip(q1[j] + s_sig * (yp.f[j] - ob), lamc[j]);
                const float q2n = clip(oq2[j] + s_sig * (xbtp - ob), lamc[j]);
                const float q0m = clip(bf_lo(qx.w[j]) + s_sig * (ob - xm.f[j]), lamx[j]);
                const float q1m = clip(bf_hi(qy.w[j]) + s_sig * (ob - ym.f[j]), lamy[j]);
                const float q2m = clip(q2tm + s_sig * (ob - xbtm), lT);
                const float dv  = (q0m - q0n) + (q1m - q1n) + (q2m - q2n);
                const float x1  = x0[j] - s_tau * (pn + dv);
                xb[j] = x1 + s_th * (x1 - x0[j]);
                x0[j] = x1; p[j] = pn;
                q0[j] = q0n; q1[j] = q1n; q2[j] = q2n;
            }
        }
    };

    substep(3);   // step 4g+1 on 14x22
    substep(2);   // step 4g+2 on 12x20
    substep(1);   // step 4g+3 on 10x18
    substep(0);   // step 4g+4 on  8x16 (own)

    // write authoritative own sites only
    if (lx >= 4 && lx < 12 && ly >= 4 && ly < 20) {
        if (LAST) {
            float4* o4 = (float4*)out_final;
            F4 a;
            a.f[0] = x0[0]; a.f[1] = x0[1]; a.f[2] = x0[2]; a.f[3] = x0[3];
            o4[c4] = a.v;
        } else {
            uint4*  o1 = (uint4*)outD1;
            float4* o2 = (float4*)outD2;
            const int base = (gcol >> 1) + 2 * tm;
            #pragma unroll
            for (int k = 0; k < 2; ++k) {
                U4 w;
                #pragma unroll
                for (int m = 0; m < 2; ++m) {
                    const int j = 2 * k + m;
                    w.w[2 * m]     = pk_bf2(xb[j], q0[j]);
                    w.w[2 * m + 1] = pk_bf2(q1[j], q2[j]);
                }
                o1[base + k] = w.v;
                F4 d;
                d.f[0] = p[2 * k];     d.f[1] = x0[2 * k];
                d.f[2] = p[2 * k + 1]; d.f[3] = x0[2 * k + 1];
                o2[base + k] = d.v;
            }
        }
    }
}

extern "C" void kernel_launch(void* const* d_in, const int* in_sizes, int n_in,
                              void* d_out, int out_size, void* d_ws, size_t ws_size,
                              hipStream_t stream) {
    const float* x   = (const float*)d_in[0];
    const float* lam = (const float*)d_in[1];
    const float* tau = (const float*)d_in[2];
    const float* sig = (const float*)d_in[3];
    const float* th  = (const float*)d_in[4];
    float* out = (float*)d_out;

    // ws layout: D1 (2 slots u64, 4 MB), D2 (2 slots u64, 4 MB)
    unsigned long long* D1 = (unsigned long long*)d_ws;
    unsigned long long* D2 = D1 + 2 * (size_t)NSITES;

    dim3 grid(NBLK), block(NTHR);

    for (int g = 0; g < NSUP; ++g) {
        const size_t si = (size_t)((g + 1) & 1) * NSITES;  // read slot (prev write)
        const size_t so = (size_t)(g & 1) * NSITES;        // write slot
        const unsigned long long *i1 = D1 + si, *i2 = D2 + si;
        unsigned long long *o1 = D1 + so, *o2 = D2 + so;
        if (g == 0) {
            pdhg_col<true, false><<<grid, block, 0, stream>>>(
                x, lam, tau, sig, th, i1, i2, o1, o2, out);
        } else if (g == NSUP - 1) {
            pdhg_col<false, true><<<grid, block, 0, stream>>>(
                x, lam, tau, sig, th, i1, i2, o1, o2, out);
        } else {
            pdhg_col<false, false><<<grid, block, 0, stream>>>(
                x, lam, tau, sig, th, i1, i2, o1, o2, out);
        }
    }
}

// Round 9
// 263.995 us; speedup vs baseline: 4.2035x; 1.0476x over previous
//
#include <hip/hip_runtime.h>
#include <math.h>

// (P, C, NX, NY, NT) = (2, 1, 128, 128, 8), T = 128
// Layout: idx = pp<<17 | X<<10 | Y<<3 | T
// R8 = R7 (276.6 us: half-T columns, 768 thr = 12 waves/CU, halo 4,
// redundancy 1.67x, b128 LDS staging, cvt_pk_bf16 packing) +
//  (1) v_med3_f32 clamps (1 inst vs min+max; IEEE min/max won't auto-fuse)
//  (2) DPP quad_perm [1,0,3,2] for all partner (xor-1) swaps — off the DS
//      pipe (was ds_bpermute), onto free VALU slots.
// Model (R2/R6/R7 fit): T/launch = 0.3us + c*work, c ~ issue-bound
// (VALU 60% / DS 40%), occupancy-independent. Both edits cut issue count;
// trajectory is BITWISE unchanged (med3 == max(-l,min(l,v)) for finite,
// DPP == shfl_xor(1)).
#define NSITES (2 * 128 * 128 * 8)      // 262144
#define NBLK   256                      // 16 bx * 8 by * 2 pp
#define NSUP   32                       // 32 launches x 4 fused steps = 128
#define TLX    16                       // staged cols x: 8 own + 4+4 halo
#define TLY    24                       // staged cols y: 16 own + 4+4 halo
#define NCOL   (TLX * TLY)              // 384 columns
#define NTHR   (NCOL * 2)               // 768 threads, 2 per column

union F4 { float4 v; float f[4]; };
union U4 { uint4 v; unsigned w[4]; };

// bf16 packing: HW v_cvt_pk_bf16_f32 (RNE, one inst). Every block rounds
// identical register values identically -> cross-block redundant-compute
// consistency is bitwise-exact.
__device__ __forceinline__ unsigned pk_bf2(float lo, float hi) {
    unsigned r;
    asm("v_cvt_pk_bf16_f32 %0, %1, %2" : "=v"(r) : "v"(lo), "v"(hi));
    return r;
}
__device__ __forceinline__ float bf_lo(unsigned p) { return __uint_as_float(p << 16); }
__device__ __forceinline__ float bf_hi(unsigned p) { return __uint_as_float(p & 0xFFFF0000u); }

// partner (lane xor 1) exchange via DPP quad_perm [1,0,3,2] — VALU pipe,
// identical semantics to __shfl_xor(x,1,64) when both partners are active
// (guaranteed: partner lanes share (lx,ly), masks are pairwise-uniform).
__device__ __forceinline__ float dpp_swap1(float x) {
    return __int_as_float(
        __builtin_amdgcn_mov_dpp(__float_as_int(x), 0xB1, 0xF, 0xF, true));
}

template <bool FIRST, bool LAST>
__global__ __launch_bounds__(NTHR, 3) void pdhg_col(
    const float* __restrict__ x,
    const float* __restrict__ lam,
    const float* __restrict__ tau_p,
    const float* __restrict__ sigma_p,
    const float* __restrict__ theta_p,
    const unsigned long long* __restrict__ inD1,   // bf16x4 {xb,q0,q1,q2}
    const unsigned long long* __restrict__ inD2,   // fp32x2 {p,x0}
    unsigned long long* __restrict__ outD1,
    unsigned long long* __restrict__ outD2,
    float* __restrict__ out_final)
{
    // [buf][t]: t = col*2 + tm, so writes/reads are t*16B +/- const (no conflicts)
    __shared__ float4 Lxb[2][NTHR];   // 24 KB  xb fp32x4 (4 T of one chunk)
    __shared__ uint4  Lqq[2][NTHR];   // 24 KB  bf16x2 {q0,q1} x4 T

    // XCD-arc swizzle (L2-locality heuristic only)
    const int b  = 32 * (blockIdx.x & 7) + (blockIdx.x >> 3);
    const int pp = b >> 7;
    const int rr = b & 127;
    const int bx = rr >> 3;        // [0,16)
    const int by = rr & 7;         // [0,8)

    const int t   = threadIdx.x;   // [0,768)
    const int tm  = t & 1;         // T-chunk: sites tm*4 .. tm*4+3
    const int col = t >> 1;        // [0,384)
    const int lx  = col / TLY;     // [0,16)
    const int ly  = col - lx * TLY;// [0,24)

    const int X  = ((bx << 3) + lx - 4) & 127;
    const int Y  = ((by << 4) + ly - 4) & 127;
    const int Xm = (X + 127) & 127;
    const int Ym = (Y + 127) & 127;

    const int gcol = (pp << 17) | (X << 10) | (Y << 3);   // site idx of T=0
    const int gxm  = (pp << 17) | (Xm << 10) | (Y << 3);
    const int gym  = (pp << 17) | (X << 10) | (Ym << 3);

    // widest computed region (h=3): lx in [1,15), ly in [1,23)
    const bool comp = (lx >= 1) && (lx < 15) && (ly >= 1) && (ly < 23);

    const float L = 3.605551275463989f;  // sqrt(13)
    const float s_sig = (1.f / (1.f + __expf(-sigma_p[0]))) / L;
    const float s_tau = (1.f / (1.f + __expf(-tau_p[0]))) / L;
    const float s_th  =  1.f / (1.f + __expf(-theta_p[0]));
    const float inv1s = 1.f / (1.f + s_sig);

    const int c4 = (gcol >> 2) + tm;   // float4 index of this chunk

    float xn[4], lamc[4], lamx[4], lamy[4];
    {
        const float4* x4 = (const float4*)x;
        const float4* l4 = (const float4*)lam;
        if (FIRST || comp) {
            F4 a; a.v = x4[c4];
            #pragma unroll
            for (int j = 0; j < 4; ++j) xn[j] = a.f[j];
        } else {
            #pragma unroll
            for (int j = 0; j < 4; ++j) xn[j] = 0.f;
        }
        if (comp) {
            F4 a;
            a.v = l4[c4];
            #pragma unroll
            for (int j = 0; j < 4; ++j) lamc[j] = a.f[j];
            a.v = l4[(gxm >> 2) + tm];
            #pragma unroll
            for (int j = 0; j < 4; ++j) lamx[j] = a.f[j];
            a.v = l4[(gym >> 2) + tm];
            #pragma unroll
            for (int j = 0; j < 4; ++j) lamy[j] = a.f[j];
        } else {
            #pragma unroll
            for (int j = 0; j < 4; ++j) { lamc[j] = 0.f; lamx[j] = 0.f; lamy[j] = 0.f; }
        }
    }
    // lam at the T-1 site of this chunk's first element = partner's lamc[3]
    const float lamtm = dpp_swap1(lamc[3]);

    float x0[4], p[4], q0[4], q1[4], q2[4], xb[4];
    if (FIRST) {
        #pragma unroll
        for (int j = 0; j < 4; ++j) {
            const float v = xn[j];
            x0[j] = v; p[j] = v; xb[j] = v;
            q0[j] = 0.f; q1[j] = 0.f; q2[j] = 0.f;
        }
    } else {
        const uint4* d1 = (const uint4*)inD1;       // 2 sites per uint4
        const int base = (gcol >> 1) + 2 * tm;      // 16B-granule index
        #pragma unroll
        for (int k = 0; k < 2; ++k) {
            U4 a; a.v = d1[base + k];
            #pragma unroll
            for (int m = 0; m < 2; ++m) {
                const int j = 2 * k + m;
                const unsigned lo = a.w[2 * m], hi = a.w[2 * m + 1];
                xb[j] = bf_lo(lo); q0[j] = bf_hi(lo);
                q1[j] = bf_lo(hi); q2[j] = bf_hi(hi);
            }
        }
        if (comp) {
            const float4* d2 = (const float4*)inD2;  // 2 sites per float4
            #pragma unroll
            for (int k = 0; k < 2; ++k) {
                F4 a; a.v = d2[base + k];
                p[2 * k]     = a.f[0]; x0[2 * k]     = a.f[1];
                p[2 * k + 1] = a.f[2]; x0[2 * k + 1] = a.f[3];
            }
        } else {
            #pragma unroll
            for (int j = 0; j < 4; ++j) { p[j] = 0.f; x0[j] = 0.f; }
        }
    }

    // clamp to [-l, l] in ONE instruction; bitwise == fmaxf(-l,fminf(l,v))
    // for finite v and l >= 0 (incl. l == 0 for masked lanes).
    auto clip = [](float v, float l) { return __builtin_amdgcn_fmed3f(v, -l, l); };

    // one fused sub-step: compute lx in [4-h,12+h), ly in [4-h,20+h)
    // store-mask = compute-region(h+1): [3-h,13+h) x [3-h,21+h)
    // Double-buffered LDS (pb = h&1): one barrier per sub-step; two barriers
    // separate reuse of the same buffer. Partner lanes share (lx,ly) so all
    // masks are pairwise-uniform and DPP partners are co-active.
    auto substep = [&](const int h) {
        const int pb = h & 1;
        if (lx >= 3 - h && lx < 13 + h && ly >= 3 - h && ly < 21 + h) {
            Lxb[pb][t] = make_float4(xb[0], xb[1], xb[2], xb[3]);
            U4 w;
            w.w[0] = pk_bf2(q0[0], q1[0]); w.w[1] = pk_bf2(q0[1], q1[1]);
            w.w[2] = pk_bf2(q0[2], q1[2]); w.w[3] = pk_bf2(q0[3], q1[3]);
            Lqq[pb][t] = w.v;
        }
        __syncthreads();
        if (lx >= 4 - h && lx < 12 + h && ly >= 4 - h && ly < 20 + h) {
            // T-boundary values from partner chunk (pre-update snapshots)
            const float xb_tp = dpp_swap1(xb[0]);  // T+1 past chunk end
            const float xb_tm = dpp_swap1(xb[3]);  // T-1 before chunk start
            const float q2_tm = dpp_swap1(q2[3]);
            F4 xp, xm, yp, ym; U4 qx, qy;
            xp.v = Lxb[pb][t + 2 * TLY];
            xm.v = Lxb[pb][t - 2 * TLY];
            yp.v = Lxb[pb][t + 2];
            ym.v = Lxb[pb][t - 2];
            qx.v = Lqq[pb][t - 2 * TLY];
            qy.v = Lqq[pb][t - 2];
            float oxb[4], oq2[4];
            #pragma unroll
            for (int j = 0; j < 4; ++j) { oxb[j] = xb[j]; oq2[j] = q2[j]; }
            #pragma unroll
            for (int j = 0; j < 4; ++j) {
                const float ob   = oxb[j];
                const float xbtp = (j < 3) ? oxb[j + 1] : xb_tp;
                const float xbtm = (j > 0) ? oxb[j - 1] : xb_tm;
                const float q2tm = (j > 0) ? oq2[j - 1] : q2_tm;
                const float lT   = (j > 0) ? lamc[j - 1] : lamtm;
                const float pn  = (p[j] + s_sig * (ob - xn[j])) * inv1s;
                const float q0n = clip(q0[j] + s_sig * (xp.f[j] - ob), lamc[j]);
                const float q1n = clip(q1[j] + s_sig * (yp.f[j] - ob), lamc[j]);
                const float q2n = clip(oq2[j] + s_sig * (xbtp - ob), lamc[j]);
                const float q0m = clip(bf_lo(qx.w[j]) + s_sig * (ob - xm.f[j]), lamx[j]);
                const float q1m = clip(bf_hi(qy.w[j]) + s_sig * (ob - ym.f[j]), lamy[j]);
                const float q2m = clip(q2tm + s_sig * (ob - xbtm), lT);
                const float dv  = (q0m - q0n) + (q1m - q1n) + (q2m - q2n);
                const float x1  = x0[j] - s_tau * (pn + dv);
                xb[j] = x1 + s_th * (x1 - x0[j]);
                x0[j] = x1; p[j] = pn;
                q0[j] = q0n; q1[j] = q1n; q2[j] = q2n;
            }
        }
    };

    substep(3);   // step 4g+1 on 14x22
    substep(2);   // step 4g+2 on 12x20
    substep(1);   // step 4g+3 on 10x18
    substep(0);   // step 4g+4 on  8x16 (own)

    // write authoritative own sites only
    if (lx >= 4 && lx < 12 && ly >= 4 && ly < 20) {
        if (LAST) {
            float4* o4 = (float4*)out_final;
            F4 a;
            a.f[0] = x0[0]; a.f[1] = x0[1]; a.f[2] = x0[2]; a.f[3] = x0[3];
            o4[c4] = a.v;
        } else {
            uint4*  o1 = (uint4*)outD1;
            float4* o2 = (float4*)outD2;
            const int base = (gcol >> 1) + 2 * tm;
            #pragma unroll
            for (int k = 0; k < 2; ++k) {
                U4 w;
                #pragma unroll
                for (int m = 0; m < 2; ++m) {
                    const int j = 2 * k + m;
                    w.w[2 * m]     = pk_bf2(xb[j], q0[j]);
                    w.w[2 * m + 1] = pk_bf2(q1[j], q2[j]);
                }
                o1[base + k] = w.v;
                F4 d;
                d.f[0] = p[2 * k];     d.f[1] = x0[2 * k];
                d.f[2] = p[2 * k + 1]; d.f[3] = x0[2 * k + 1];
                o2[base + k] = d.v;
            }
        }
    }
}

extern "C" void kernel_launch(void* const* d_in, const int* in_sizes, int n_in,
                              void* d_out, int out_size, void* d_ws, size_t ws_size,
                              hipStream_t stream) {
    const float* x   = (const float*)d_in[0];
    const float* lam = (const float*)d_in[1];
    const float* tau = (const float*)d_in[2];
    const float* sig = (const float*)d_in[3];
    const float* th  = (const float*)d_in[4];
    float* out = (float*)d_out;

    // ws layout: D1 (2 slots u64, 4 MB), D2 (2 slots u64, 4 MB)
    unsigned long long* D1 = (unsigned long long*)d_ws;
    unsigned long long* D2 = D1 + 2 * (size_t)NSITES;

    dim3 grid(NBLK), block(NTHR);

    for (int g = 0; g < NSUP; ++g) {
        const size_t si = (size_t)((g + 1) & 1) * NSITES;  // read slot (prev write)
        const size_t so = (size_t)(g & 1) * NSITES;        // write slot
        const unsigned long long *i1 = D1 + si, *i2 = D2 + si;
        unsigned long long *o1 = D1 + so, *o2 = D2 + so;
        if (g == 0) {
            pdhg_col<true, false><<<grid, block, 0, stream>>>(
                x, lam, tau, sig, th, i1, i2, o1, o2, out);
        } else if (g == NSUP - 1) {
            pdhg_col<false, true><<<grid, block, 0, stream>>>(
                x, lam, tau, sig, th, i1, i2, o1, o2, out);
        } else {
            pdhg_col<false, false><<<grid, block, 0, stream>>>(
                x, lam, tau, sig, th, i1, i2, o1, o2, out);
        }
    }
}

// Round 10
// 255.449 us; speedup vs baseline: 4.3441x; 1.0335x over previous
//
#include <hip/hip_runtime.h>
#include <math.h>

// (P, C, NX, NY, NT) = (2, 1, 128, 128, 8), T = 128
// Layout: idx = pp<<17 | X<<10 | Y<<3 | T
// R10: exchange-not-recompute. Key identity: q0m[site x] == q0n[site x-1]
// computed the SAME substep (and q1m == y-1's q1n, q2m == t-1's q2n).
// Old scheme recomputed the m-values from bf16-staged OLD q (9 VALU + 2 LDS
// reads + 2 unpacks per site) — new scheme splits the substep:
//   A: stage xb, bar, read xp/yp, q-update in place, stage NEW q0,q1 (fp32)
//   B: bar, read qx,qy (= exact m-values, 0 VALU), p/x/xb update
// Drops lamx/lamy/lamtm entirely. DS reads 6->4; +1 barrier/substep.
// fp32 q staging = FEWER roundings than R9 (m-path now exact) -> absmax <=.
// Cross-block consistency still bitwise (identical ops on identical D1/D2).
// Base: R9 (264 us: half-T columns, 768 thr, halo 4, med3 clips, DPP swaps,
// cvt_pk_bf16 for D1 epilogue).
#define NSITES (2 * 128 * 128 * 8)      // 262144
#define NBLK   256                      // 16 bx * 8 by * 2 pp
#define NSUP   32                       // 32 launches x 4 fused steps = 128
#define TLX    16                       // staged cols x: 8 own + 4+4 halo
#define TLY    24                       // staged cols y: 16 own + 4+4 halo
#define NCOL   (TLX * TLY)              // 384 columns
#define NTHR   (NCOL * 2)               // 768 threads, 2 per column

union F4 { float4 v; float f[4]; };
union U4 { uint4 v; unsigned w[4]; };

// bf16 packing: HW v_cvt_pk_bf16_f32 (RNE, one inst) — D1 epilogue only now.
__device__ __forceinline__ unsigned pk_bf2(float lo, float hi) {
    unsigned r;
    asm("v_cvt_pk_bf16_f32 %0, %1, %2" : "=v"(r) : "v"(lo), "v"(hi));
    return r;
}
__device__ __forceinline__ float bf_lo(unsigned p) { return __uint_as_float(p << 16); }
__device__ __forceinline__ float bf_hi(unsigned p) { return __uint_as_float(p & 0xFFFF0000u); }

// partner (lane xor 1) exchange via DPP quad_perm [1,0,3,2] — VALU pipe.
// Partner lanes share (lx,ly): all masks pairwise-uniform, partners co-active.
__device__ __forceinline__ float dpp_swap1(float x) {
    return __int_as_float(
        __builtin_amdgcn_mov_dpp(__float_as_int(x), 0xB1, 0xF, 0xF, true));
}

template <bool FIRST, bool LAST>
__global__ __launch_bounds__(NTHR, 3) void pdhg_col(
    const float* __restrict__ x,
    const float* __restrict__ lam,
    const float* __restrict__ tau_p,
    const float* __restrict__ sigma_p,
    const float* __restrict__ theta_p,
    const unsigned long long* __restrict__ inD1,   // bf16x4 {xb,q0,q1,q2}
    const unsigned long long* __restrict__ inD2,   // fp32x2 {p,x0}
    unsigned long long* __restrict__ outD1,
    unsigned long long* __restrict__ outD2,
    float* __restrict__ out_final)
{
    // single-buffered: reads of an array and its next overwrite are always
    // separated by >=1 __syncthreads (which drains lgkmcnt before s_barrier).
    __shared__ float4 Lxb[NTHR];   // 12 KB  xb fp32x4 (4 T of one chunk)
    __shared__ float4 Lq0[NTHR];   // 12 KB  NEW q0 fp32x4
    __shared__ float4 Lq1[NTHR];   // 12 KB  NEW q1 fp32x4

    // XCD-arc swizzle (L2-locality heuristic only)
    const int b  = 32 * (blockIdx.x & 7) + (blockIdx.x >> 3);
    const int pp = b >> 7;
    const int rr = b & 127;
    const int bx = rr >> 3;        // [0,16)
    const int by = rr & 7;         // [0,8)

    const int t   = threadIdx.x;   // [0,768)
    const int tm  = t & 1;         // T-chunk: sites tm*4 .. tm*4+3
    const int col = t >> 1;        // [0,384)
    const int lx  = col / TLY;     // [0,16)
    const int ly  = col - lx * TLY;// [0,24)

    const int X  = ((bx << 3) + lx - 4) & 127;
    const int Y  = ((by << 4) + ly - 4) & 127;

    const int gcol = (pp << 17) | (X << 10) | (Y << 3);   // site idx of T=0

    // x-phase widest region R(3): lx in [1,15), ly in [1,23)
    const bool comp = (lx >= 1) && (lx < 15) && (ly >= 1) && (ly < 23);

    const float L = 3.605551275463989f;  // sqrt(13)
    const float s_sig = (1.f / (1.f + __expf(-sigma_p[0]))) / L;
    const float s_tau = (1.f / (1.f + __expf(-tau_p[0]))) / L;
    const float s_th  =  1.f / (1.f + __expf(-theta_p[0]));
    const float inv1s = 1.f / (1.f + s_sig);

    const int c4 = (gcol >> 2) + tm;   // float4 index of this chunk

    // invariant inputs, loaded unconditionally (all addresses valid; lamc is
    // needed on the full q-region Q(3) = [0,15)x[0,23) incl. edges)
    float xn[4], lamc[4];
    {
        const float4* x4 = (const float4*)x;
        const float4* l4 = (const float4*)lam;
        F4 a;
        a.v = x4[c4];
        #pragma unroll
        for (int j = 0; j < 4; ++j) xn[j] = a.f[j];
        a.v = l4[c4];
        #pragma unroll
        for (int j = 0; j < 4; ++j) lamc[j] = a.f[j];
    }

    float x0[4], p[4], q0[4], q1[4], q2[4], xb[4];
    if (FIRST) {
        #pragma unroll
        for (int j = 0; j < 4; ++j) {
            const float v = xn[j];
            x0[j] = v; p[j] = v; xb[j] = v;
            q0[j] = 0.f; q1[j] = 0.f; q2[j] = 0.f;
        }
    } else {
        const uint4* d1 = (const uint4*)inD1;       // 2 sites per uint4
        const int base = (gcol >> 1) + 2 * tm;      // 16B-granule index
        #pragma unroll
        for (int k = 0; k < 2; ++k) {
            U4 a; a.v = d1[base + k];
            #pragma unroll
            for (int m = 0; m < 2; ++m) {
                const int j = 2 * k + m;
                const unsigned lo = a.w[2 * m], hi = a.w[2 * m + 1];
                xb[j] = bf_lo(lo); q0[j] = bf_hi(lo);
                q1[j] = bf_lo(hi); q2[j] = bf_hi(hi);
            }
        }
        if (comp) {
            const float4* d2 = (const float4*)inD2;  // 2 sites per float4
            #pragma unroll
            for (int k = 0; k < 2; ++k) {
                F4 a; a.v = d2[base + k];
                p[2 * k]     = a.f[0]; x0[2 * k]     = a.f[1];
                p[2 * k + 1] = a.f[2]; x0[2 * k + 1] = a.f[3];
            }
        } else {
            #pragma unroll
            for (int j = 0; j < 4; ++j) { p[j] = 0.f; x0[j] = 0.f; }
        }
    }

    // clamp to [-l, l] in ONE instruction (l >= 0 everywhere)
    auto clip = [](float v, float l) { return __builtin_amdgcn_fmed3f(v, -l, l); };

    // one fused sub-step h:
    //  xb-store S(h): lx in [3-h,13+h), ly in [3-h,21+h)   (xb current on R(h+1) == S(h))
    //  q-phase  Q(h): lx in [3-h,12+h), ly in [3-h,20+h)   (needs xp/yp in S(h))
    //  x-phase  R(h): lx in [4-h,12+h), ly in [4-h,20+h)   (needs qx/qy in Q(h))
    auto substep = [&](const int h) {
        // -------- Phase A: xb staging + q-update --------
        if (lx >= 3 - h && lx < 13 + h && ly >= 3 - h && ly < 21 + h) {
            Lxb[t] = make_float4(xb[0], xb[1], xb[2], xb[3]);
        }
        __syncthreads();
        const bool inQ = (lx >= 3 - h) && (lx < 12 + h) &&
                         (ly >= 3 - h) && (ly < 20 + h);
        if (inQ) {
            F4 xp, yp;
            xp.v = Lxb[t + 2 * TLY];
            yp.v = Lxb[t + 2];
            const float xb_tp = dpp_swap1(xb[0]);  // partner's xb[0] = T+1 wrap
            #pragma unroll
            for (int j = 0; j < 4; ++j) {
                const float ob   = xb[j];
                const float xbtp = (j < 3) ? xb[j + 1] : xb_tp;
                q0[j] = clip(q0[j] + s_sig * (xp.f[j] - ob), lamc[j]);
                q1[j] = clip(q1[j] + s_sig * (yp.f[j] - ob), lamc[j]);
                q2[j] = clip(q2[j] + s_sig * (xbtp   - ob), lamc[j]);
            }
            Lq0[t] = make_float4(q0[0], q0[1], q0[2], q0[3]);
            Lq1[t] = make_float4(q1[0], q1[1], q1[2], q1[3]);
        }
        // -------- Phase B: m-exchange + p/x/xb update --------
        __syncthreads();
        if (lx >= 4 - h && lx < 12 + h && ly >= 4 - h && ly < 20 + h) {
            F4 qx, qy;
            qx.v = Lq0[t - 2 * TLY];               // x-1's NEW q0 == q0m (exact)
            qy.v = Lq1[t - 2];                     // y-1's NEW q1 == q1m (exact)
            const float q2_tm = dpp_swap1(q2[3]);  // partner's NEW q2[3] = T-1 wrap
            #pragma unroll
            for (int j = 0; j < 4; ++j) {
                const float ob  = xb[j];
                const float pn  = (p[j] + s_sig * (ob - xn[j])) * inv1s;
                const float q2m = (j > 0) ? q2[j - 1] : q2_tm;
                const float dv  = (qx.f[j] - q0[j]) + (qy.f[j] - q1[j]) + (q2m - q2[j]);
                const float x1  = x0[j] - s_tau * (pn + dv);
                xb[j] = x1 + s_th * (x1 - x0[j]);
                x0[j] = x1; p[j] = pn;
            }
        }
    };

    substep(3);   // step 4g+1 on 14x22
    substep(2);   // step 4g+2 on 12x20
    substep(1);   // step 4g+3 on 10x18
    substep(0);   // step 4g+4 on  8x16 (own)

    // write authoritative own sites only
    if (lx >= 4 && lx < 12 && ly >= 4 && ly < 20) {
        if (LAST) {
            float4* o4 = (float4*)out_final;
            F4 a;
            a.f[0] = x0[0]; a.f[1] = x0[1]; a.f[2] = x0[2]; a.f[3] = x0[3];
            o4[c4] = a.v;
        } else {
            uint4*  o1 = (uint4*)outD1;
            float4* o2 = (float4*)outD2;
            const int base = (gcol >> 1) + 2 * tm;
            #pragma unroll
            for (int k = 0; k < 2; ++k) {
                U4 w;
                #pragma unroll
                for (int m = 0; m < 2; ++m) {
                    const int j = 2 * k + m;
                    w.w[2 * m]     = pk_bf2(xb[j], q0[j]);
                    w.w[2 * m + 1] = pk_bf2(q1[j], q2[j]);
                }
                o1[base + k] = w.v;
                F4 d;
                d.f[0] = p[2 * k];     d.f[1] = x0[2 * k];
                d.f[2] = p[2 * k + 1]; d.f[3] = x0[2 * k + 1];
                o2[base + k] = d.v;
            }
        }
    }
}

extern "C" void kernel_launch(void* const* d_in, const int* in_sizes, int n_in,
                              void* d_out, int out_size, void* d_ws, size_t ws_size,
                              hipStream_t stream) {
    const float* x   = (const float*)d_in[0];
    const float* lam = (const float*)d_in[1];
    const float* tau = (const float*)d_in[2];
    const float* sig = (const float*)d_in[3];
    const float* th  = (const float*)d_in[4];
    float* out = (float*)d_out;

    // ws layout: D1 (2 slots u64, 4 MB), D2 (2 slots u64, 4 MB)
    unsigned long long* D1 = (unsigned long long*)d_ws;
    unsigned long long* D2 = D1 + 2 * (size_t)NSITES;

    dim3 grid(NBLK), block(NTHR);

    for (int g = 0; g < NSUP; ++g) {
        const size_t si = (size_t)((g + 1) & 1) * NSITES;  // read slot (prev write)
        const size_t so = (size_t)(g & 1) * NSITES;        // write slot
        const unsigned long long *i1 = D1 + si, *i2 = D2 + si;
        unsigned long long *o1 = D1 + so, *o2 = D2 + so;
        if (g == 0) {
            pdhg_col<true, false><<<grid, block, 0, stream>>>(
                x, lam, tau, sig, th, i1, i2, o1, o2, out);
        } else if (g == NSUP - 1) {
            pdhg_col<false, true><<<grid, block, 0, stream>>>(
                x, lam, tau, sig, th, i1, i2, o1, o2, out);
        } else {
            pdhg_col<false, false><<<grid, block, 0, stream>>>(
                x, lam, tau, sig, th, i1, i2, o1, o2, out);
        }
    }
}

// Round 11
// 246.673 us; speedup vs baseline: 4.4987x; 1.0356x over previous
//
#include <hip/hip_runtime.h>
#include <math.h>

// (P, C, NX, NY, NT) = (2, 1, 128, 128, 8), T = 128
// Layout: idx = pp<<17 | X<<10 | Y<<3 | T
// R11 = R10 (255.4 us: exchange-not-recompute, half-T columns, 768 thr,
// halo 4, med3 clips, DPP swaps) + PACKED FP32 (VOP3P v_pk_fma/add/mul_f32,
// full-rate on gfx950): all pairable math over T-sites (0,1)/(2,3) written
// as ext_vector float2 -> one inst per 2 floats. med3 stays scalar (no pk
// variant). xb-store fused into phase B (S(h-1) == R(h)). Bitwise-identical
// trajectory (pk ops are per-element IEEE fma/add/mul, same order).
#define NSITES (2 * 128 * 128 * 8)      // 262144
#define NBLK   256                      // 16 bx * 8 by * 2 pp
#define NSUP   32                       // 32 launches x 4 fused steps = 128
#define TLX    16                       // staged cols x: 8 own + 4+4 halo
#define TLY    24                       // staged cols y: 16 own + 4+4 halo
#define NCOL   (TLX * TLY)              // 384 columns
#define NTHR   (NCOL * 2)               // 768 threads, 2 per column

typedef float v2f __attribute__((ext_vector_type(2)));

union F4 { float4 v; float f[4]; v2f h[2]; };
union U4 { uint4 v; unsigned w[4]; };

// bf16 packing: HW v_cvt_pk_bf16_f32 (RNE, one inst) — D1 epilogue only.
__device__ __forceinline__ unsigned pk_bf2(float lo, float hi) {
    unsigned r;
    asm("v_cvt_pk_bf16_f32 %0, %1, %2" : "=v"(r) : "v"(lo), "v"(hi));
    return r;
}
__device__ __forceinline__ float bf_lo(unsigned p) { return __uint_as_float(p << 16); }
__device__ __forceinline__ float bf_hi(unsigned p) { return __uint_as_float(p & 0xFFFF0000u); }

// partner (lane xor 1) exchange via DPP quad_perm [1,0,3,2] — VALU pipe.
// Partner lanes share (lx,ly): all masks pairwise-uniform, partners co-active.
__device__ __forceinline__ float dpp_swap1(float x) {
    return __int_as_float(
        __builtin_amdgcn_mov_dpp(__float_as_int(x), 0xB1, 0xF, 0xF, true));
}

__device__ __forceinline__ float med3(float v, float lo, float hi) {
    return __builtin_amdgcn_fmed3f(v, lo, hi);
}

template <bool FIRST, bool LAST>
__global__ __launch_bounds__(NTHR, 3) void pdhg_col(
    const float* __restrict__ x,
    const float* __restrict__ lam,
    const float* __restrict__ tau_p,
    const float* __restrict__ sigma_p,
    const float* __restrict__ theta_p,
    const unsigned long long* __restrict__ inD1,   // bf16x4 {xb,q0,q1,q2}
    const unsigned long long* __restrict__ inD2,   // fp32x2 {p,x0}
    unsigned long long* __restrict__ outD1,
    unsigned long long* __restrict__ outD2,
    float* __restrict__ out_final)
{
    // single-buffered: every write->read and read->overwrite pair of the same
    // array is separated by >=1 __syncthreads (drains lgkmcnt at s_barrier).
    __shared__ float4 Lxb[NTHR];   // 12 KB  xb fp32x4 (4 T of one chunk)
    __shared__ float4 Lq0[NTHR];   // 12 KB  NEW q0 fp32x4
    __shared__ float4 Lq1[NTHR];   // 12 KB  NEW q1 fp32x4

    // XCD-arc swizzle (L2-locality heuristic only)
    const int b  = 32 * (blockIdx.x & 7) + (blockIdx.x >> 3);
    const int pp = b >> 7;
    const int rr = b & 127;
    const int bx = rr >> 3;        // [0,16)
    const int by = rr & 7;         // [0,8)

    const int t   = threadIdx.x;   // [0,768)
    const int tm  = t & 1;         // T-chunk: sites tm*4 .. tm*4+3
    const int col = t >> 1;        // [0,384)
    const int lx  = col / TLY;     // [0,16)
    const int ly  = col - lx * TLY;// [0,24)

    const int X  = ((bx << 3) + lx - 4) & 127;
    const int Y  = ((by << 4) + ly - 4) & 127;

    const int gcol = (pp << 17) | (X << 10) | (Y << 3);   // site idx of T=0

    // x-phase widest region R(3): lx in [1,15), ly in [1,23)
    const bool comp = (lx >= 1) && (lx < 15) && (ly >= 1) && (ly < 23);

    const float L = 3.605551275463989f;  // sqrt(13)
    const float s_sig = (1.f / (1.f + __expf(-sigma_p[0]))) / L;
    const float s_tau = (1.f / (1.f + __expf(-tau_p[0]))) / L;
    const float s_th  =  1.f / (1.f + __expf(-theta_p[0]));
    const float inv1s = 1.f / (1.f + s_sig);

    const v2f sig2   = { s_sig, s_sig };
    const v2f inv1s2 = { inv1s, inv1s };
    const v2f ntau2  = { -s_tau, -s_tau };
    const v2f th2    = { s_th, s_th };

    const int c4 = (gcol >> 2) + tm;   // float4 index of this chunk

    // invariant inputs, loaded unconditionally (lamc needed on full Q(3))
    v2f xnv[2], lamv[2];
    {
        const float4* x4 = (const float4*)x;
        const float4* l4 = (const float4*)lam;
        F4 a;
        a.v = x4[c4];
        xnv[0] = a.h[0]; xnv[1] = a.h[1];
        a.v = l4[c4];
        lamv[0] = a.h[0]; lamv[1] = a.h[1];
    }

    v2f x0v[2], pv[2], q0v[2], q1v[2], q2v[2], xbv[2];
    if (FIRST) {
        #pragma unroll
        for (int k = 0; k < 2; ++k) {
            x0v[k] = xnv[k]; pv[k] = xnv[k]; xbv[k] = xnv[k];
            q0v[k] = (v2f){0.f, 0.f}; q1v[k] = (v2f){0.f, 0.f}; q2v[k] = (v2f){0.f, 0.f};
        }
    } else {
        const uint4* d1 = (const uint4*)inD1;       // 2 sites per uint4
        const int base = (gcol >> 1) + 2 * tm;      // 16B-granule index
        #pragma unroll
        for (int k = 0; k < 2; ++k) {
            U4 a; a.v = d1[base + k];
            xbv[k] = (v2f){ bf_lo(a.w[0]), bf_lo(a.w[2]) };
            q0v[k] = (v2f){ bf_hi(a.w[0]), bf_hi(a.w[2]) };
            q1v[k] = (v2f){ bf_lo(a.w[1]), bf_lo(a.w[3]) };
            q2v[k] = (v2f){ bf_hi(a.w[1]), bf_hi(a.w[3]) };
        }
        if (comp) {
            const float4* d2 = (const float4*)inD2;  // 2 sites per float4
            #pragma unroll
            for (int k = 0; k < 2; ++k) {
                F4 a; a.v = d2[base + k];
                pv[k]  = (v2f){ a.f[0], a.f[2] };
                x0v[k] = (v2f){ a.f[1], a.f[3] };
            }
        } else {
            #pragma unroll
            for (int k = 0; k < 2; ++k) { pv[k] = (v2f){0.f,0.f}; x0v[k] = (v2f){0.f,0.f}; }
        }
    }

    // stage xb for substep(3): S(3) = full tile, unconditional
    {
        F4 s; s.h[0] = xbv[0]; s.h[1] = xbv[1];
        Lxb[t] = s.v;
    }

    // one fused sub-step h:
    //  q-phase  Q(h): lx in [3-h,12+h), ly in [3-h,20+h)  (reads Lxb; stores Lq)
    //  x-phase  R(h): lx in [4-h,12+h), ly in [4-h,20+h)  (reads Lq; stores Lxb
    //                 for next substep — S(h-1) == R(h) — skipped at h==0)
    auto substep = [&](const int h) {
        __syncthreads();
        // -------- Phase A: q-update (packed) --------
        if (lx >= 3 - h && lx < 12 + h && ly >= 3 - h && ly < 20 + h) {
            F4 xp, yp;
            xp.v = Lxb[t + 2 * TLY];
            yp.v = Lxb[t + 2];
            const float xb_tp = dpp_swap1(xbv[0].x);   // partner xb[0] = T+1 wrap
            const v2f tp0 = { xbv[0].y, xbv[1].x };    // xb shifted by +1 in T
            const v2f tp1 = { xbv[1].y, xb_tp };
            #pragma unroll
            for (int k = 0; k < 2; ++k) {
                const v2f t0 = __builtin_elementwise_fma(sig2, xp.h[k] - xbv[k], q0v[k]);
                const v2f t1 = __builtin_elementwise_fma(sig2, yp.h[k] - xbv[k], q1v[k]);
                const v2f t2 = __builtin_elementwise_fma(sig2, (k ? tp1 : tp0) - xbv[k], q2v[k]);
                q0v[k].x = med3(t0.x, -lamv[k].x, lamv[k].x);
                q0v[k].y = med3(t0.y, -lamv[k].y, lamv[k].y);
                q1v[k].x = med3(t1.x, -lamv[k].x, lamv[k].x);
                q1v[k].y = med3(t1.y, -lamv[k].y, lamv[k].y);
                q2v[k].x = med3(t2.x, -lamv[k].x, lamv[k].x);
                q2v[k].y = med3(t2.y, -lamv[k].y, lamv[k].y);
            }
            F4 s0, s1;
            s0.h[0] = q0v[0]; s0.h[1] = q0v[1];
            s1.h[0] = q1v[0]; s1.h[1] = q1v[1];
            Lq0[t] = s0.v;
            Lq1[t] = s1.v;
        }
        __syncthreads();
        // -------- Phase B: m-exchange + p/x/xb update (packed) --------
        if (lx >= 4 - h && lx < 12 + h && ly >= 4 - h && ly < 20 + h) {
            F4 qx, qy;
            qx.v = Lq0[t - 2 * TLY];                   // x-1's NEW q0 == q0m (exact)
            qy.v = Lq1[t - 2];                         // y-1's NEW q1 == q1m (exact)
            const float q2_tm = dpp_swap1(q2v[1].y);   // partner NEW q2[3] = T-1 wrap
            const v2f q2m0 = { q2_tm, q2v[0].x };      // NEW q2 shifted by -1 in T
            const v2f q2m1 = { q2v[0].y, q2v[1].x };
            #pragma unroll
            for (int k = 0; k < 2; ++k) {
                v2f pn = __builtin_elementwise_fma(sig2, xbv[k] - xnv[k], pv[k]);
                pn = pn * inv1s2;
                const v2f dv = ((qx.h[k] - q0v[k]) + (qy.h[k] - q1v[k]))
                             + ((k ? q2m1 : q2m0) - q2v[k]);
                const v2f x1 = __builtin_elementwise_fma(ntau2, pn + dv, x0v[k]);
                xbv[k] = __builtin_elementwise_fma(th2, x1 - x0v[k], x1);
                x0v[k] = x1; pv[k] = pn;
            }
            if (h > 0) {                               // stage xb for next substep
                F4 s; s.h[0] = xbv[0]; s.h[1] = xbv[1];
                Lxb[t] = s.v;
            }
        }
    };

    substep(3);   // step 4g+1 on 14x22
    substep(2);   // step 4g+2 on 12x20
    substep(1);   // step 4g+3 on 10x18
    substep(0);   // step 4g+4 on  8x16 (own)

    // write authoritative own sites only
    if (lx >= 4 && lx < 12 && ly >= 4 && ly < 20) {
        if (LAST) {
            float4* o4 = (float4*)out_final;
            F4 a;
            a.f[0] = x0v[0].x; a.f[1] = x0v[0].y;
            a.f[2] = x0v[1].x; a.f[3] = x0v[1].y;
            o4[c4] = a.v;
        } else {
            uint4*  o1 = (uint4*)outD1;
            float4* o2 = (float4*)outD2;
            const int base = (gcol >> 1) + 2 * tm;
            #pragma unroll
            for (int k = 0; k < 2; ++k) {
                U4 w;
                w.w[0] = pk_bf2(xbv[k].x, q0v[k].x);
                w.w[1] = pk_bf2(q1v[k].x, q2v[k].x);
                w.w[2] = pk_bf2(xbv[k].y, q0v[k].y);
                w.w[3] = pk_bf2(q1v[k].y, q2v[k].y);
                o1[base + k] = w.v;
                F4 d;
                d.f[0] = pv[k].x; d.f[1] = x0v[k].x;
                d.f[2] = pv[k].y; d.f[3] = x0v[k].y;
                o2[base + k] = d.v;
            }
        }
    }
}

extern "C" void kernel_launch(void* const* d_in, const int* in_sizes, int n_in,
                              void* d_out, int out_size, void* d_ws, size_t ws_size,
                              hipStream_t stream) {
    const float* x   = (const float*)d_in[0];
    const float* lam = (const float*)d_in[1];
    const float* tau = (const float*)d_in[2];
    const float* sig = (const float*)d_in[3];
    const float* th  = (const float*)d_in[4];
    float* out = (float*)d_out;

    // ws layout: D1 (2 slots u64, 4 MB), D2 (2 slots u64, 4 MB)
    unsigned long long* D1 = (unsigned long long*)d_ws;
    unsigned long long* D2 = D1 + 2 * (size_t)NSITES;

    dim3 grid(NBLK), block(NTHR);

    for (int g = 0; g < NSUP; ++g) {
        const size_t si = (size_t)((g + 1) & 1) * NSITES;  // read slot (prev write)
        const size_t so = (size_t)(g & 1) * NSITES;        // write slot
        const unsigned long long *i1 = D1 + si, *i2 = D2 + si;
        unsigned long long *o1 = D1 + so, *o2 = D2 + so;
        if (g == 0) {
            pdhg_col<true, false><<<grid, block, 0, stream>>>(
                x, lam, tau, sig, th, i1, i2, o1, o2, out);
        } else if (g == NSUP - 1) {
            pdhg_col<false, true><<<grid, block, 0, stream>>>(
                x, lam, tau, sig, th, i1, i2, o1, o2, out);
        } else {
            pdhg_col<false, false><<<grid, block, 0, stream>>>(
                x, lam, tau, sig, th, i1, i2, o1, o2, out);
        }
    }
}